// Round 1
// baseline (2288.934 us; speedup 1.0000x reference)
//
#include <hip/hip_runtime.h>
#include <cstddef>
#include <math.h>

#define L_DIM 256
#define E_DIM 768
#define H_DIM 384
#define NEG_INF_F (-1e9f)

__device__ __forceinline__ float wave_reduce_sum(float v) {
#pragma unroll
    for (int off = 32; off > 0; off >>= 1) v += __shfl_xor(v, off, 64);
    return v;
}

// ---------------------------------------------------------------------------
// Fused mask-attention pooling with online softmax: ONE pass over bert_feature.
// One block per batch row b. 256 threads = 4 waves; wave w handles l in
// [64w, 64w+64). Each lane keeps e-fragment {lane*4.., +64*4.., +128*4..}
// (3 float4 = 12 floats) of the running pooled accumulator in registers.
// ---------------------------------------------------------------------------
__global__ __launch_bounds__(256) void attn_pool_kernel(
    const float* __restrict__ feat,   // [B, L, E]
    const int*   __restrict__ masks,  // [B, L]
    const float* __restrict__ att_w,  // [E]
    const float* __restrict__ att_b,  // [1]
    float* __restrict__ pooled)       // [B, E]
{
    const int b    = blockIdx.x;
    const int tid  = threadIdx.x;
    const int lane = tid & 63;
    const int wid  = tid >> 6;

    __shared__ int    msk[L_DIM];
    __shared__ float  wm[4], wdn[4];
    __shared__ float4 accbuf[4][192];

    msk[tid] = masks[b * L_DIM + tid];
    __syncthreads();

    const float4* aw4 = reinterpret_cast<const float4*>(att_w);
    const float4  w0 = aw4[lane], w1 = aw4[lane + 64], w2 = aw4[lane + 128];
    const float   ab = att_b[0];

    const float4* frow =
        reinterpret_cast<const float4*>(feat + (size_t)b * L_DIM * E_DIM);

    float  m = -INFINITY, den = 0.f;
    float4 a0 = make_float4(0.f, 0.f, 0.f, 0.f);
    float4 a1 = make_float4(0.f, 0.f, 0.f, 0.f);
    float4 a2 = make_float4(0.f, 0.f, 0.f, 0.f);

    const int lbeg = wid * 64;
    for (int l = lbeg; l < lbeg + 64; ++l) {
        const float4* fl = frow + (size_t)l * 192;
        const float4 f0 = fl[lane], f1 = fl[lane + 64], f2 = fl[lane + 128];

        float p = f0.x * w0.x + f0.y * w0.y + f0.z * w0.z + f0.w * w0.w
                + f1.x * w1.x + f1.y * w1.y + f1.z * w1.z + f1.w * w1.w
                + f2.x * w2.x + f2.y * w2.y + f2.z * w2.z + f2.w * w2.w;
        p = wave_reduce_sum(p);
        float s = p + ab;
        if (msk[l] == 0) s = NEG_INF_F;

        if (s > m) {                      // wave-uniform branch (s uniform)
            const float sc = __expf(m - s);   // m=-inf on first iter -> 0
            a0.x *= sc; a0.y *= sc; a0.z *= sc; a0.w *= sc;
            a1.x *= sc; a1.y *= sc; a1.z *= sc; a1.w *= sc;
            a2.x *= sc; a2.y *= sc; a2.z *= sc; a2.w *= sc;
            den *= sc;
            m = s;
        }
        const float pe = __expf(s - m);
        den += pe;
        a0.x += pe * f0.x; a0.y += pe * f0.y; a0.z += pe * f0.z; a0.w += pe * f0.w;
        a1.x += pe * f1.x; a1.y += pe * f1.y; a1.z += pe * f1.z; a1.w += pe * f1.w;
        a2.x += pe * f2.x; a2.y += pe * f2.y; a2.z += pe * f2.z; a2.w += pe * f2.w;
    }

    if (lane == 0) { wm[wid] = m; wdn[wid] = den; }
    __syncthreads();

    const float M4 = fmaxf(fmaxf(wm[0], wm[1]), fmaxf(wm[2], wm[3]));
    const float D  = wdn[0] * __expf(wm[0] - M4) + wdn[1] * __expf(wm[1] - M4)
                   + wdn[2] * __expf(wm[2] - M4) + wdn[3] * __expf(wm[3] - M4);
    const float ew = __expf(wm[wid] - M4);

    a0.x *= ew; a0.y *= ew; a0.z *= ew; a0.w *= ew;
    a1.x *= ew; a1.y *= ew; a1.z *= ew; a1.w *= ew;
    a2.x *= ew; a2.y *= ew; a2.z *= ew; a2.w *= ew;
    accbuf[wid][lane]       = a0;
    accbuf[wid][lane + 64]  = a1;
    accbuf[wid][lane + 128] = a2;
    __syncthreads();

    if (tid < 192) {
        const float inv = 1.f / D;
        float4 r0 = accbuf[0][tid], r1 = accbuf[1][tid],
               r2 = accbuf[2][tid], r3 = accbuf[3][tid];
        float4 r;
        r.x = (r0.x + r1.x + r2.x + r3.x) * inv;
        r.y = (r0.y + r1.y + r2.y + r3.y) * inv;
        r.z = (r0.z + r1.z + r2.z + r3.z) * inv;
        r.w = (r0.w + r1.w + r2.w + r3.w) * inv;
        reinterpret_cast<float4*>(pooled + (size_t)b * E_DIM)[tid] = r;
    }
}

// ---------------------------------------------------------------------------
// Single-block bucketing: group sample indices by category (9 buckets).
// ---------------------------------------------------------------------------
__global__ __launch_bounds__(256) void bucket_kernel(
    const int* __restrict__ cat, int B,
    int* __restrict__ idxbuf, int* __restrict__ offs)
{
    __shared__ int cnt[9];
    __shared__ int pos[9];
    const int tid = threadIdx.x;
    if (tid < 9) cnt[tid] = 0;
    __syncthreads();
    for (int i = tid; i < B; i += 256) atomicAdd(&cnt[cat[i]], 1);
    __syncthreads();
    if (tid == 0) {
        int s = 0;
        for (int c = 0; c < 9; ++c) { pos[c] = s; offs[c] = s; s += cnt[c]; }
        offs[9] = s;
    }
    __syncthreads();
    for (int i = tid; i < B; i += 256) {
        const int p = atomicAdd(&pos[cat[i]], 1);
        idxbuf[p] = i;
    }
}

// ---------------------------------------------------------------------------
// Generic fp32 tiled GEMM: C[r, n] = act( sum_k A[row(r), k] * W[k, n] + b[n] )
// 64x64 tile, BK=16, 256 threads, 4x4 micro-tile. Optional category routing:
// catoff != nullptr -> blockIdx.z selects category c; rows come from
// idx[catoff[c]..catoff[c+1]), W += c*wstride, bias += c*bstride.
// ---------------------------------------------------------------------------
__global__ __launch_bounds__(256) void gemm_kernel(
    const float* __restrict__ A, int lda,
    const float* __restrict__ W, int N,      // W: [K, N] row-major
    const float* __restrict__ bias,
    float* __restrict__ C, int ldc,
    int M, int K,
    const int* __restrict__ rowidx,
    const int* __restrict__ catoff,
    long wstride, int bstride, int relu)
{
    int rs = 0, re = M;
    if (catoff) {
        const int c = blockIdx.z;
        rs = catoff[c];
        re = catoff[c + 1];
        W    += (size_t)c * wstride;
        bias += (size_t)c * bstride;
    }
    const int row0 = rs + blockIdx.y * 64;
    if (row0 >= re) return;
    const int n0 = blockIdx.x * 64;

    __shared__ float As[16][65];
    __shared__ __align__(16) float Bs[16][64];

    const int tid = threadIdx.x;
    const int ar = tid >> 2, ak = (tid & 3) << 2;
    const int bk = tid >> 4, bn = (tid & 15) << 2;
    const int tx = tid & 15, ty = tid >> 4;

    const float* Aptr = nullptr;
    {
        const int arow = row0 + ar;
        if (arow < re) {
            const int ridx = rowidx ? rowidx[arow] : arow;
            Aptr = A + (size_t)ridx * lda;
        }
    }

    float acc[4][4] = {};

    for (int k0 = 0; k0 < K; k0 += 16) {
        float4 av = make_float4(0.f, 0.f, 0.f, 0.f);
        if (Aptr) av = *reinterpret_cast<const float4*>(Aptr + k0 + ak);
        const float4 bv =
            *reinterpret_cast<const float4*>(W + (size_t)(k0 + bk) * N + n0 + bn);
        As[ak + 0][ar] = av.x;
        As[ak + 1][ar] = av.y;
        As[ak + 2][ar] = av.z;
        As[ak + 3][ar] = av.w;
        *reinterpret_cast<float4*>(&Bs[bk][bn]) = bv;
        __syncthreads();
#pragma unroll
        for (int kk = 0; kk < 16; ++kk) {
            const float a0v = As[kk][ty * 4 + 0];
            const float a1v = As[kk][ty * 4 + 1];
            const float a2v = As[kk][ty * 4 + 2];
            const float a3v = As[kk][ty * 4 + 3];
            const float4 b4 = *reinterpret_cast<const float4*>(&Bs[kk][tx * 4]);
            acc[0][0] += a0v * b4.x; acc[0][1] += a0v * b4.y;
            acc[0][2] += a0v * b4.z; acc[0][3] += a0v * b4.w;
            acc[1][0] += a1v * b4.x; acc[1][1] += a1v * b4.y;
            acc[1][2] += a1v * b4.z; acc[1][3] += a1v * b4.w;
            acc[2][0] += a2v * b4.x; acc[2][1] += a2v * b4.y;
            acc[2][2] += a2v * b4.z; acc[2][3] += a2v * b4.w;
            acc[3][0] += a3v * b4.x; acc[3][1] += a3v * b4.y;
            acc[3][2] += a3v * b4.z; acc[3][3] += a3v * b4.w;
        }
        __syncthreads();
    }

    const float bb0 = bias[n0 + tx * 4 + 0];
    const float bb1 = bias[n0 + tx * 4 + 1];
    const float bb2 = bias[n0 + tx * 4 + 2];
    const float bb3 = bias[n0 + tx * 4 + 3];

#pragma unroll
    for (int i = 0; i < 4; ++i) {
        const int rr = row0 + ty * 4 + i;
        if (rr < re) {
            const int cr = rowidx ? rowidx[rr] : rr;
            float v0 = acc[i][0] + bb0;
            float v1 = acc[i][1] + bb1;
            float v2 = acc[i][2] + bb2;
            float v3 = acc[i][3] + bb3;
            if (relu) {
                v0 = fmaxf(v0, 0.f); v1 = fmaxf(v1, 0.f);
                v2 = fmaxf(v2, 0.f); v3 = fmaxf(v3, 0.f);
            }
            float4 v = make_float4(v0, v1, v2, v3);
            *reinterpret_cast<float4*>(C + (size_t)cr * ldc + n0 + tx * 4) = v;
        }
    }
}

// ---------------------------------------------------------------------------
// out[r] = sigmoid(dot(feature[r, 0:768], Wc) + bc). One wave per row.
// ---------------------------------------------------------------------------
__global__ __launch_bounds__(256) void head_out_kernel(
    const float* __restrict__ feature, const float* __restrict__ Wc,
    const float* __restrict__ bc, float* __restrict__ out)
{
    const int lane = threadIdx.x & 63;
    const int wid  = threadIdx.x >> 6;
    const int r    = blockIdx.x * 4 + wid;

    const float4* wc4 = reinterpret_cast<const float4*>(Wc);
    const float4 w0 = wc4[lane], w1 = wc4[lane + 64], w2 = wc4[lane + 128];
    const float4* fr =
        reinterpret_cast<const float4*>(feature + (size_t)r * 768);
    const float4 f0 = fr[lane], f1 = fr[lane + 64], f2 = fr[lane + 128];

    float p = f0.x * w0.x + f0.y * w0.y + f0.z * w0.z + f0.w * w0.w
            + f1.x * w1.x + f1.y * w1.y + f1.z * w1.z + f1.w * w1.w
            + f2.x * w2.x + f2.y * w2.y + f2.z * w2.z + f2.w * w2.w;
    p = wave_reduce_sum(p);
    if (lane == 0) {
        const float z = p + bc[0];
        out[r] = 1.f / (1.f + __expf(-z));
    }
}

// ---------------------------------------------------------------------------
// domain_pred[r, c] = dot(h[r, :384], Wdo2[:, c]) + bdo2[c]. One wave per row.
// ---------------------------------------------------------------------------
__global__ __launch_bounds__(256) void head_dp_kernel(
    const float* __restrict__ h, const float* __restrict__ Wdo2,
    const float* __restrict__ bdo2, float* __restrict__ dp)
{
    __shared__ float w2[H_DIM * 9];
    __shared__ float b2[9];
    const int tid = threadIdx.x;
    for (int i = tid; i < H_DIM * 9; i += 256) w2[i] = Wdo2[i];
    if (tid < 9) b2[tid] = bdo2[tid];
    __syncthreads();

    const int lane = tid & 63;
    const int wid  = tid >> 6;
    const int r    = blockIdx.x * 4 + wid;

    const float* hr = h + (size_t)r * H_DIM;
    float hv[6];
#pragma unroll
    for (int j = 0; j < 6; ++j) hv[j] = hr[lane + 64 * j];

#pragma unroll
    for (int c = 0; c < 9; ++c) {
        float p = 0.f;
#pragma unroll
        for (int j = 0; j < 6; ++j) p += hv[j] * w2[(lane + 64 * j) * 9 + c];
        p = wave_reduce_sum(p);
        if (lane == 0) dp[r * 9 + c] = p + b2[c];
    }
}

// ---------------------------------------------------------------------------
extern "C" void kernel_launch(void* const* d_in, const int* in_sizes, int n_in,
                              void* d_out, int out_size, void* d_ws,
                              size_t ws_size, hipStream_t stream)
{
    const float* feat     = (const float*)d_in[0];
    const int*   masks    = (const int*)d_in[1];
    const int*   category = (const int*)d_in[2];
    // d_in[3] = alpha (unused in forward: gradient reversal is identity)
    const float* att_w = (const float*)d_in[4];
    const float* att_b = (const float*)d_in[5];
    const float* Wsh   = (const float*)d_in[6];
    const float* bsh   = (const float*)d_in[7];
    const float* Wsp   = (const float*)d_in[8];
    const float* bsp   = (const float*)d_in[9];
    const float* Wd1   = (const float*)d_in[10];
    const float* bd1   = (const float*)d_in[11];
    const float* Wd2   = (const float*)d_in[12];
    const float* bd2   = (const float*)d_in[13];
    const float* Wc    = (const float*)d_in[14];
    const float* bc    = (const float*)d_in[15];
    const float* Wdo1  = (const float*)d_in[16];
    const float* bdo1  = (const float*)d_in[17];
    const float* Wdo2  = (const float*)d_in[18];
    const float* bdo2  = (const float*)d_in[19];

    const int B = in_sizes[0] / (L_DIM * E_DIM);   // 2048

    // d_out layout: out[B] | rec[B*E] | pooled[B*E] | domain_pred[B*9]
    float* out    = (float*)d_out;
    float* rec    = out + B;
    float* pooled = rec + (size_t)B * E_DIM;
    float* dp     = pooled + (size_t)B * E_DIM;

    // workspace layout (floats): feature[B*768] | t[B*64] | h[B*384] | ints
    float* feature = (float*)d_ws;
    float* tbuf    = feature + (size_t)B * (2 * H_DIM);
    float* hbuf    = tbuf + (size_t)B * 64;
    int*   idxbuf  = (int*)(hbuf + (size_t)B * H_DIM);
    int*   offs    = idxbuf + B;

    // 1. attention pooling -> pooled (also an output)
    attn_pool_kernel<<<B, 256, 0, stream>>>(feat, masks, att_w, att_b, pooled);

    // 2. bucket samples by category
    bucket_kernel<<<1, 256, 0, stream>>>(category, B, idxbuf, offs);

    // 3. shared MLP: feature[:, 0:384] = relu(pooled @ Wsh + bsh)
    gemm_kernel<<<dim3(H_DIM / 64, (B + 63) / 64, 1), 256, 0, stream>>>(
        pooled, E_DIM, Wsh, H_DIM, bsh, feature, 2 * H_DIM, B, E_DIM,
        nullptr, nullptr, 0, 0, 1);

    // 4. routed specific MLP: feature[:, 384:768] = relu(pooled @ Wsp[cat] + bsp[cat])
    gemm_kernel<<<dim3(H_DIM / 64, (B + 63) / 64, 9), 256, 0, stream>>>(
        pooled, E_DIM, Wsp, H_DIM, bsp, feature + H_DIM, 2 * H_DIM, B, E_DIM,
        idxbuf, offs, (long)E_DIM * H_DIM, H_DIM, 1);

    // 5. t = relu(feature @ Wd1 + bd1)  [B, 64]
    gemm_kernel<<<dim3(1, (B + 63) / 64, 1), 256, 0, stream>>>(
        feature, 2 * H_DIM, Wd1, 64, bd1, tbuf, 64, B, 2 * H_DIM,
        nullptr, nullptr, 0, 0, 1);

    // 6. rec = relu(t @ Wd2 + bd2)  [B, 768] -> output
    gemm_kernel<<<dim3(E_DIM / 64, (B + 63) / 64, 1), 256, 0, stream>>>(
        tbuf, 64, Wd2, E_DIM, bd2, rec, E_DIM, B, 64,
        nullptr, nullptr, 0, 0, 1);

    // 7. out = sigmoid(feature @ Wc + bc) -> output
    head_out_kernel<<<B / 4, 256, 0, stream>>>(feature, Wc, bc, out);

    // 8. h = relu(shared @ Wdo1 + bdo1)  (shared = feature[:, 0:384], lda=768)
    gemm_kernel<<<dim3(H_DIM / 64, (B + 63) / 64, 1), 256, 0, stream>>>(
        feature, 2 * H_DIM, Wdo1, H_DIM, bdo1, hbuf, H_DIM, B, H_DIM,
        nullptr, nullptr, 0, 0, 1);

    // 9. domain_pred = h @ Wdo2 + bdo2 -> output
    head_dp_kernel<<<B / 4, 256, 0, stream>>>(hbuf, Wdo2, bdo2, dp);
}